// Round 21
// baseline (72.929 us; speedup 1.0000x reference)
//
#include <hip/hip_runtime.h>

// Problem constants (b=8, h=w=32, m=8 heads, d=64, c=512)
#define Dd 64
#define Cc 512
#define HW 1024
#define BM 64            // b*m
#define LOG2E 1.44269504f

typedef __attribute__((ext_vector_type(8))) short bf16x8;
typedef __attribute__((ext_vector_type(4))) short bf16x4;
typedef __attribute__((ext_vector_type(4))) float f32x4;

__device__ __forceinline__ unsigned short f2bf(float f) {
  unsigned int u = __builtin_bit_cast(unsigned int, f);
  u += 0x7fffu + ((u >> 16) & 1u);
  return (unsigned short)(u >> 16);
}

// pack 2 fp32 -> 2 bf16 in one dword (scalar RNE pack — PROVEN; inline-asm
// v_cvt_pk_bf16_f32 produced garbage on this toolchain: R3-R6 NaNs)
__device__ __forceinline__ unsigned int pack2(float lo, float hi) {
  return (unsigned int)f2bf(lo) | ((unsigned int)f2bf(hi) << 16);
}

// 16B-granular XOR swizzle for [rows][64 bf16] LDS tiles (row stride 128B).
__device__ __forceinline__ int swz(int row, int cb) {
  return row * 128 + (cb ^ ((row & 7) << 4));
}

// ---------------------------------------------------------------------------
// K1 (PROVEN R12): QKV projection as swapped MFMA GEMM.
// Q,K written [bm][pos][d]; V written TRANSPOSED [bm][d][pos].
// ---------------------------------------------------------------------------
__global__ __launch_bounds__(256, 2) void qkv_kernel(
    const float* __restrict__ x, const float* __restrict__ w,
    const float* __restrict__ bqkv,
    unsigned short* __restrict__ Q, unsigned short* __restrict__ K,
    unsigned short* __restrict__ Vt) {
  __shared__ unsigned short Wt[192 * 64];  // [n'][k] swizzled
  __shared__ float bl[192];
  char* WtB = (char*)Wt;
  int t = threadIdx.x, lane = t & 63, wv = t >> 6;
  int c = lane & 15, r4 = lane >> 4;
  int bm = blockIdx.x >> 4;
  int pos0 = (blockIdx.x & 15) * 64;
  int bb = bm >> 3, mm = bm & 7;

  for (int idx = t; idx < 12288; idx += 256) {
    int k = idx / 192, col = idx - (idx / 192) * 192;
    int d3 = col / 3, which = col - d3 * 3;
    int np = which * 64 + d3;
    float v = w[idx];
    if (which == 0) v *= 0.125f;  // q / sqrt(64)
    *(unsigned short*)(WtB + np * 128 + ((k * 2) ^ ((np & 7) << 4))) = f2bf(v);
  }
  if (t < 192) {
    int d3 = t / 3, which = t - d3 * 3;
    float bvv = bqkv[t];
    if (which == 0) bvv *= 0.125f;
    bl[which * 64 + d3] = bvv;
  }
  __syncthreads();

  bf16x8 af[12][2];
#pragma unroll
  for (int nf = 0; nf < 12; ++nf) {
    int row = nf * 16 + c, sw = (row & 7) << 4;
#pragma unroll
    for (int kc = 0; kc < 2; ++kc)
      af[nf][kc] = *(const bf16x8*)(WtB + row * 128 + ((kc * 64 + r4 * 16) ^ sw));
  }
  f32x4 acc[12];
#pragma unroll
  for (int nf = 0; nf < 12; ++nf)
    acc[nf] = *(const f32x4*)&bl[nf * 16 + r4 * 4];

  int pos = pos0 + wv * 16 + c;
  const float* xr = x + (size_t)(bb * HW + pos) * Cc + mm * Dd;
  bf16x8 xb[2];
#pragma unroll
  for (int kc = 0; kc < 2; ++kc) {
    f32x4 lo = *(const f32x4*)(xr + kc * 32 + r4 * 8);
    f32x4 hi = *(const f32x4*)(xr + kc * 32 + r4 * 8 + 4);
    union { unsigned int u[4]; bf16x8 b; } cv;
    cv.u[0] = pack2(lo[0], lo[1]);
    cv.u[1] = pack2(lo[2], lo[3]);
    cv.u[2] = pack2(hi[0], hi[1]);
    cv.u[3] = pack2(hi[2], hi[3]);
    xb[kc] = cv.b;
  }
#pragma unroll
  for (int nf = 0; nf < 12; ++nf) {
    acc[nf] = __builtin_amdgcn_mfma_f32_16x16x32_bf16(af[nf][0], xb[0], acc[nf], 0, 0, 0);
    acc[nf] = __builtin_amdgcn_mfma_f32_16x16x32_bf16(af[nf][1], xb[1], acc[nf], 0, 0, 0);
  }
  size_t obase = ((size_t)bm * HW + pos) * Dd;
#pragma unroll
  for (int nf = 0; nf < 8; ++nf) {  // Q, K: [bm][pos][d] b64 packed
    unsigned int d0 = pack2(acc[nf][0], acc[nf][1]);
    unsigned int d1 = pack2(acc[nf][2], acc[nf][3]);
    unsigned long long wd = (unsigned long long)d0 | ((unsigned long long)d1 << 32);
    unsigned short* dst = (nf < 4) ? Q : K;
    *(unsigned long long*)(dst + obase + (nf & 3) * 16 + r4 * 4) = wd;
  }
#pragma unroll
  for (int nf = 8; nf < 12; ++nf) {  // V transposed: [bm][d][pos]
#pragma unroll
    for (int reg = 0; reg < 4; ++reg) {
      int d = (nf - 8) * 16 + r4 * 4 + reg;
      Vt[((size_t)bm * Dd + d) * HW + pos] = f2bf(acc[nf][reg]);
    }
  }
}

// ---------------------------------------------------------------------------
// K2 (v8 = v7 structure at 64-row i-tiles for 4 blocks/CU): the serial
// QK^T->softmax->PV chain needs >=4 waves/SIMD to interleave pipes; v7 was
// grid-capped at 2. R10's 64-row regression causes (V-transpose conflicts,
// LDS bias gathers) are both fixed, so retry at high occupancy.
// LDS 40KB/block -> 4 blocks/CU. Single h per wave (16 i-rows).
// ---------------------------------------------------------------------------
__global__ __launch_bounds__(256, 4) void attn_kernel(
    const unsigned short* __restrict__ Q, const unsigned short* __restrict__ K,
    const unsigned short* __restrict__ Vt, const float* __restrict__ pe,
    unsigned short* __restrict__ O) {
  __shared__ unsigned short Kt[2][64 * 64];  // [buf][j][k] swizzled, 16KB
  __shared__ unsigned short Vl[2][64 * 64];  // [buf][d][j] swizzled, 16KB
  __shared__ unsigned short Pl[4][1024];     // per wave [i=c][j], 8KB
  char* PlB = (char*)Pl;
  int t = threadIdx.x, lane = t & 63, wv = t >> 6;
  int c = lane & 15, r4 = lane >> 4;
  // bijective XCD swizzle (1024 % 8 == 0): 8 consecutive bm per XCD
  int swzid = (blockIdx.x & 7) * 128 + (blockIdx.x >> 3);
  int bm = swzid >> 4;
  int i0 = (swzid & 15) * 64;

  // Q B-frags: lane col i = c, k = kc*32 + r4*8 + e
  const unsigned short* Qb = Q + ((size_t)bm * HW + i0 + wv * 16) * Dd;
  bf16x8 qb[2];
#pragma unroll
  for (int kc = 0; kc < 2; ++kc)
    qb[kc] = *(const bf16x8*)(Qb + c * Dd + kc * 32 + r4 * 8);

  // bias base: pe idx = hb + 63*(j0>>5) + const(jf) + reg
  int ibase = i0 + wv * 16;
  int yi = ibase >> 5, xib = ibase & 31;
  int hb = 63 * (31 - yi) + 31 - xib - c + r4 * 4;

  f32x4 oacc[4];
  float m_run = -1e30f, l_run = 0.f;
#pragma unroll
  for (int nf = 0; nf < 4; ++nf) oacc[nf] = {0.f, 0.f, 0.f, 0.f};

  const unsigned short* Kg = K + (size_t)bm * HW * Dd;
  const unsigned short* Vg = Vt + (size_t)bm * Dd * HW;  // V^T [d][pos]
  char* pb = PlB + wv * 2048 + c * 128;
  int swp = (c & 7) << 4;
  int srow = t >> 3, sc8 = t & 7;  // staging role

  bf16x8 kreg[2], vreg[2];
  auto issue = [&](int j0) {
#pragma unroll
    for (int rep = 0; rep < 2; ++rep) {
      int row = srow + rep * 32;
      kreg[rep] = *(const bf16x8*)(Kg + (size_t)(j0 + row) * Dd + sc8 * 8);
      vreg[rep] = *(const bf16x8*)(Vg + (size_t)row * HW + j0 + sc8 * 8);
    }
  };
  auto stage = [&](int buf) {
#pragma unroll
    for (int rep = 0; rep < 2; ++rep) {
      int row = srow + rep * 32;
      *(bf16x8*)((char*)Kt[buf] + swz(row, sc8 * 16)) = kreg[rep];
      *(bf16x8*)((char*)Vl[buf] + swz(row, sc8 * 16)) = vreg[rep];
    }
  };

  // prologue: tile 0 -> buf0; tile 1 loads in flight
  issue(0);
  stage(0);
  issue(64);
  __syncthreads();

  int cur = 0;
  for (int jt = 0; jt < 16; ++jt) {
    int j0 = jt * 64;
    // stage tile jt+1 and issue tile jt+2 first (loads hide under compute)
    if (jt < 15) {
      stage(cur ^ 1);
      if (jt < 14) issue(j0 + 128);
    }
    char* KtB = (char*)Kt[cur];
    char* VtB = (char*)Vl[cur];

    // bias-seeded accumulators from GLOBAL pe: S^T[j][i]
    f32x4 sacc[4];
    int tb = hb + 63 * (j0 >> 5);
#pragma unroll
    for (int jf = 0; jf < 4; ++jf) {
      int o = tb + (jf >> 1) * 63 + (jf & 1) * 16;
      sacc[jf] = {pe[o], pe[o + 1], pe[o + 2], pe[o + 3]};
    }
    // QK^T (A = K rows j from LDS, B = Q cols i)
#pragma unroll
    for (int jf = 0; jf < 4; ++jf) {
      int row = jf * 16 + c, sw = (row & 7) << 4;
      bf16x8 kb0 = *(const bf16x8*)(KtB + row * 128 + ((r4 * 16) ^ sw));
      bf16x8 kb1 = *(const bf16x8*)(KtB + row * 128 + ((64 + r4 * 16) ^ sw));
      sacc[jf] = __builtin_amdgcn_mfma_f32_16x16x32_bf16(kb0, qb[0], sacc[jf], 0, 0, 0);
      sacc[jf] = __builtin_amdgcn_mfma_f32_16x16x32_bf16(kb1, qb[1], sacc[jf], 0, 0, 0);
    }
    // online softmax (defer-max THR=8; j lane-local)
    float mx = fmaxf(
        fmaxf(fmaxf(fmaxf(sacc[0][0], sacc[0][1]), fmaxf(sacc[0][2], sacc[0][3])),
              fmaxf(fmaxf(sacc[1][0], sacc[1][1]), fmaxf(sacc[1][2], sacc[1][3]))),
        fmaxf(fmaxf(fmaxf(sacc[2][0], sacc[2][1]), fmaxf(sacc[2][2], sacc[2][3])),
              fmaxf(fmaxf(sacc[3][0], sacc[3][1]), fmaxf(sacc[3][2], sacc[3][3]))));
    mx = fmaxf(mx, __shfl_xor(mx, 16));
    mx = fmaxf(mx, __shfl_xor(mx, 32));
    if (!__all(mx <= m_run + 8.f)) {  // T13: rescale only on max growth
      float mnew = fmaxf(m_run, mx);
      float sc = __builtin_amdgcn_exp2f((m_run - mnew) * LOG2E);
      m_run = mnew;
      l_run *= sc;
#pragma unroll
      for (int nf = 0; nf < 4; ++nf) oacc[nf] *= sc;
    }
    float ml = m_run * LOG2E;
    float ps = 0.f;
#pragma unroll
    for (int jf = 0; jf < 4; ++jf)
#pragma unroll
      for (int r = 0; r < 4; ++r) {
        float p = __builtin_amdgcn_exp2f(fmaf(sacc[jf][r], LOG2E, -ml));
        sacc[jf][r] = p;
        ps += p;
      }
    ps += __shfl_xor(ps, 16);
    ps += __shfl_xor(ps, 32);
    l_run += ps;
    // pack P -> wave-private LDS [i=c][j] (b64, swizzled; no barrier)
#pragma unroll
    for (int jf = 0; jf < 4; ++jf) {
      unsigned int w0 = pack2(sacc[jf][0], sacc[jf][1]);
      unsigned int w1 = pack2(sacc[jf][2], sacc[jf][3]);
      unsigned long long wd = (unsigned long long)w0 | ((unsigned long long)w1 << 32);
      *(unsigned long long*)(pb + ((jf * 32 + r4 * 8) ^ swp)) = wd;
    }
    // PV: O^T = V^T · P^T (A = V^T rows d from LDS, B = P^T cols i)
#pragma unroll
    for (int jk = 0; jk < 2; ++jk) {
      bf16x8 pa = *(const bf16x8*)(pb + ((jk * 64 + r4 * 16) ^ swp));
#pragma unroll
      for (int nf = 0; nf < 4; ++nf) {
        int row = nf * 16 + c, sw = (row & 7) << 4;
        bf16x8 vb = *(const bf16x8*)(VtB + row * 128 + ((jk * 64 + r4 * 16) ^ sw));
        oacc[nf] = __builtin_amdgcn_mfma_f32_16x16x32_bf16(vb, pa, oacc[nf], 0, 0, 0);
      }
    }
    if (jt < 15) {
      __syncthreads();  // single barrier per tile
      cur ^= 1;
    }
  }

  // epilogue (R10-proven): normalize, transpose via per-wave LDS zone,
  // coalesced b128 stores
  __syncthreads();
  char* zone = ((wv < 2) ? (char*)Kt[0] : (char*)Vl[0]) + (wv & 1) * 4096;
  float inv = 1.f / l_run;
  int swc = (c & 7) << 4;
#pragma unroll
  for (int nf = 0; nf < 4; ++nf) {
    unsigned int d0 = pack2(oacc[nf][0] * inv, oacc[nf][1] * inv);
    unsigned int d1 = pack2(oacc[nf][2] * inv, oacc[nf][3] * inv);
    unsigned long long wd = (unsigned long long)d0 | ((unsigned long long)d1 << 32);
    *(unsigned long long*)(zone + c * 128 + ((nf * 32 + r4 * 8) ^ swc)) = wd;
  }
  __syncthreads();
  int rrow = lane >> 2, dq = lane & 3;
  int swr = (rrow & 7) << 4;
  size_t obase = ((size_t)bm * HW + i0 + wv * 16 + rrow) * Dd + dq * 16;
#pragma unroll
  for (int p = 0; p < 2; ++p) {
    bf16x8 vv = *(const bf16x8*)(zone + rrow * 128 + ((dq * 32 + p * 16) ^ swr));
    *(bf16x8*)(O + obase + p * 8) = vv;
  }
}

// ---------------------------------------------------------------------------
// K3 (R20 v2): output projection, bf16 MFMA, dbuf 1-barrier pipeline.
// ---------------------------------------------------------------------------
__global__ __launch_bounds__(256, 2) void proj_kernel(
    const unsigned short* __restrict__ O, const float* __restrict__ W,
    const float* __restrict__ bias, float* __restrict__ out) {
  __shared__ unsigned short Aq[2][128 * 64];  // [buf][row][k] swizzled, 32KB
  __shared__ unsigned short Bt[2][64 * 64];   // [buf][n][k] swizzled, 16KB
  int t = threadIdx.x, lane = t & 63, wv = t >> 6;
  int rb = blockIdx.x >> 3, n0 = (blockIdx.x & 7) * 64;
  int row0 = rb * 128;             // flat (b,pos); never crosses b
  int b = row0 >> 10, pos0 = row0 & 1023;
  int c = lane & 15, r4 = lane >> 4;
  int nt = t & 15, kt = t >> 4;    // B staging roles

  f32x4 acc[2][4];
#pragma unroll
  for (int g = 0; g < 2; ++g)
#pragma unroll
    for (int nf = 0; nf < 4; ++nf) acc[g][nf] = {0.f, 0.f, 0.f, 0.f};

  bf16x8 areg[4];
  f32x4 wreg[4];

  auto issue = [&](int m) {
#pragma unroll
    for (int rep = 0; rep < 4; ++rep) {
      int cid = t + rep * 256;
      int row = cid >> 3, c8 = cid & 7;
      areg[rep] = *(const bf16x8*)(O + ((size_t)(b * 8 + m) * HW + pos0 + row) * Dd + c8 * 8);
    }
#pragma unroll
    for (int r = 0; r < 4; ++r)
      wreg[r] = *(const f32x4*)(W + (size_t)(m * 64 + kt * 4 + r) * Cc + n0 + nt * 4);
  };
  auto stage = [&](int buf) {
    char* AqB = (char*)Aq[buf];
    char* BtB = (char*)Bt[buf];
#pragma unroll
    for (int rep = 0; rep < 4; ++rep) {
      int cid = t + rep * 256;
      int row = cid >> 3, c8 = cid & 7;
      *(bf16x8*)(AqB + swz(row, c8 * 16)) = areg[rep];
    }
#pragma unroll
    for (int e = 0; e < 4; ++e) {
      bf16x4 bt = {(short)f2bf(wreg[0][e]), (short)f2bf(wreg[1][e]),
                   (short)f2bf(wreg[2][e]), (short)f2bf(wreg[3][e])};
      *(bf16x4*)(BtB + swz(nt * 4 + e, kt * 8)) = bt;
    }
  };

  issue(0);
  stage(0);
  issue(1);
  __syncthreads();

  int cur = 0;
  for (int m = 0; m < 8; ++m) {
    if (m < 7) {
      stage(cur ^ 1);
      if (m < 6) issue(m + 2);
    }
    char* AqB = (char*)Aq[cur];
    char* BtB = (char*)Bt[cur];
#pragma unroll
    for (int kc = 0; kc < 2; ++kc) {
      bf16x8 a0 = *(const bf16x8*)(AqB + swz(wv * 32 + c, kc * 64 + r4 * 16));
      bf16x8 a1 = *(const bf16x8*)(AqB + swz(wv * 32 + 16 + c, kc * 64 + r4 * 16));
#pragma unroll
      for (int nf = 0; nf < 4; ++nf) {
        bf16x8 bb = *(const bf16x8*)(BtB + swz(nf * 16 + c, kc * 64 + r4 * 16));
        acc[0][nf] = __builtin_amdgcn_mfma_f32_16x16x32_bf16(a0, bb, acc[0][nf], 0, 0, 0);
        acc[1][nf] = __builtin_amdgcn_mfma_f32_16x16x32_bf16(a1, bb, acc[1][nf], 0, 0, 0);
      }
    }
    if (m < 7) {
      __syncthreads();
      cur ^= 1;
    }
  }

  float bv[4];
#pragma unroll
  for (int nf = 0; nf < 4; ++nf) bv[nf] = bias[n0 + nf * 16 + c];
#pragma unroll
  for (int g = 0; g < 2; ++g) {
#pragma unroll
    for (int reg = 0; reg < 4; ++reg) {
      int row = row0 + wv * 32 + g * 16 + r4 * 4 + reg;
#pragma unroll
      for (int nf = 0; nf < 4; ++nf)
        out[(size_t)row * Cc + n0 + nf * 16 + c] = acc[g][nf][reg] + bv[nf];
    }
  }
}

extern "C" void kernel_launch(void* const* d_in, const int* in_sizes, int n_in,
                              void* d_out, int out_size, void* d_ws, size_t ws_size,
                              hipStream_t stream) {
  const float* x      = (const float*)d_in[0];
  const float* qkv_w  = (const float*)d_in[1];
  const float* qkv_b  = (const float*)d_in[2];
  const float* pos_emb= (const float*)d_in[3];
  const float* ht_w   = (const float*)d_in[4];
  const float* ht_b   = (const float*)d_in[5];
  float* out = (float*)d_out;

  const size_t NQ = (size_t)BM * HW * Dd;  // 4,194,304 elements
  unsigned short* Qw  = (unsigned short*)d_ws;
  unsigned short* Kw  = Qw + NQ;
  unsigned short* Vtw = Kw + NQ;           // V^T [bm][d][pos], 8 MB
  unsigned short* Ow  = Vtw + NQ;          // bf16 O [bm][pos][d], 8 MB

  hipLaunchKernelGGL(qkv_kernel, dim3(1024), dim3(256), 0, stream,
                     x, qkv_w, qkv_b, Qw, Kw, Vtw);
  hipLaunchKernelGGL(attn_kernel, dim3(1024), dim3(256), 0, stream,
                     Qw, Kw, Vtw, pos_emb, Ow);
  hipLaunchKernelGGL(proj_kernel, dim3(512), dim3(256), 0, stream,
                     Ow, ht_w, ht_b, out);
}

// Round 22
// 71.654 us; speedup vs baseline: 1.0178x; 1.0178x over previous
//
#include <hip/hip_runtime.h>

// Problem constants (b=8, h=w=32, m=8 heads, d=64, c=512)
#define Dd 64
#define Cc 512
#define HW 1024
#define BM 64            // b*m
#define LOG2E 1.44269504f

typedef __attribute__((ext_vector_type(8))) short bf16x8;
typedef __attribute__((ext_vector_type(4))) short bf16x4;
typedef __attribute__((ext_vector_type(4))) float f32x4;

__device__ __forceinline__ unsigned short f2bf(float f) {
  unsigned int u = __builtin_bit_cast(unsigned int, f);
  u += 0x7fffu + ((u >> 16) & 1u);
  return (unsigned short)(u >> 16);
}

// pack 2 fp32 -> 2 bf16 in one dword (scalar RNE pack — PROVEN; inline-asm
// v_cvt_pk_bf16_f32 produced garbage on this toolchain: R3-R6 NaNs)
__device__ __forceinline__ unsigned int pack2(float lo, float hi) {
  return (unsigned int)f2bf(lo) | ((unsigned int)f2bf(hi) << 16);
}

// 16B-granular XOR swizzle for [rows][64 bf16] LDS tiles (row stride 128B).
__device__ __forceinline__ int swz(int row, int cb) {
  return row * 128 + (cb ^ ((row & 7) << 4));
}

// ---------------------------------------------------------------------------
// K1 (v2: 4x W-stage amortization): QKV as swapped MFMA GEMM. Grid 256
// (bm x 4 pos-chunks of 256). W' staged to LDS ONCE, A-frags register-
// resident; the pos-loop is pure global->cvt->MFMA->store (no LDS/barrier).
// Q,K written [bm][pos][d]; V written TRANSPOSED [bm][d][pos].
// ---------------------------------------------------------------------------
__global__ __launch_bounds__(256, 2) void qkv_kernel(
    const float* __restrict__ x, const float* __restrict__ w,
    const float* __restrict__ bqkv,
    unsigned short* __restrict__ Q, unsigned short* __restrict__ K,
    unsigned short* __restrict__ Vt) {
  __shared__ unsigned short Wt[192 * 64];  // [n'][k] swizzled
  __shared__ float bl[192];
  char* WtB = (char*)Wt;
  int t = threadIdx.x, lane = t & 63, wv = t >> 6;
  int c = lane & 15, r4 = lane >> 4;
  int bm = blockIdx.x >> 2;
  int chunk0 = (blockIdx.x & 3) * 256;
  int bb = bm >> 3, mm = bm & 7;

  for (int idx = t; idx < 12288; idx += 256) {
    int k = idx / 192, col = idx - (idx / 192) * 192;
    int d3 = col / 3, which = col - d3 * 3;
    int np = which * 64 + d3;
    float v = w[idx];
    if (which == 0) v *= 0.125f;  // q / sqrt(64)
    *(unsigned short*)(WtB + np * 128 + ((k * 2) ^ ((np & 7) << 4))) = f2bf(v);
  }
  if (t < 192) {
    int d3 = t / 3, which = t - d3 * 3;
    float bvv = bqkv[t];
    if (which == 0) bvv *= 0.125f;
    bl[which * 64 + d3] = bvv;
  }
  __syncthreads();

  bf16x8 af[12][2];
#pragma unroll
  for (int nf = 0; nf < 12; ++nf) {
    int row = nf * 16 + c, sw = (row & 7) << 4;
#pragma unroll
    for (int kc = 0; kc < 2; ++kc)
      af[nf][kc] = *(const bf16x8*)(WtB + row * 128 + ((kc * 64 + r4 * 16) ^ sw));
  }
  f32x4 bseed[12];
#pragma unroll
  for (int nf = 0; nf < 12; ++nf)
    bseed[nf] = *(const f32x4*)&bl[nf * 16 + r4 * 4];

  for (int pg = 0; pg < 4; ++pg) {
    int pos = chunk0 + pg * 64 + wv * 16 + c;
    const float* xr = x + (size_t)(bb * HW + pos) * Cc + mm * Dd;
    bf16x8 xb[2];
#pragma unroll
    for (int kc = 0; kc < 2; ++kc) {
      f32x4 lo = *(const f32x4*)(xr + kc * 32 + r4 * 8);
      f32x4 hi = *(const f32x4*)(xr + kc * 32 + r4 * 8 + 4);
      union { unsigned int u[4]; bf16x8 b; } cv;
      cv.u[0] = pack2(lo[0], lo[1]);
      cv.u[1] = pack2(lo[2], lo[3]);
      cv.u[2] = pack2(hi[0], hi[1]);
      cv.u[3] = pack2(hi[2], hi[3]);
      xb[kc] = cv.b;
    }
    f32x4 acc[12];
#pragma unroll
    for (int nf = 0; nf < 12; ++nf) {
      acc[nf] = bseed[nf];
      acc[nf] = __builtin_amdgcn_mfma_f32_16x16x32_bf16(af[nf][0], xb[0], acc[nf], 0, 0, 0);
      acc[nf] = __builtin_amdgcn_mfma_f32_16x16x32_bf16(af[nf][1], xb[1], acc[nf], 0, 0, 0);
    }
    size_t obase = ((size_t)bm * HW + pos) * Dd;
#pragma unroll
    for (int nf = 0; nf < 8; ++nf) {  // Q, K: [bm][pos][d] b64 packed
      unsigned int d0 = pack2(acc[nf][0], acc[nf][1]);
      unsigned int d1 = pack2(acc[nf][2], acc[nf][3]);
      unsigned long long wd = (unsigned long long)d0 | ((unsigned long long)d1 << 32);
      unsigned short* dst = (nf < 4) ? Q : K;
      *(unsigned long long*)(dst + obase + (nf & 3) * 16 + r4 * 4) = wd;
    }
#pragma unroll
    for (int nf = 8; nf < 12; ++nf) {  // V transposed: [bm][d][pos]
#pragma unroll
      for (int reg = 0; reg < 4; ++reg) {
        int d = (nf - 8) * 16 + r4 * 4 + reg;
        Vt[((size_t)bm * Dd + d) * HW + pos] = f2bf(acc[nf][reg]);
      }
    }
  }
}

// ---------------------------------------------------------------------------
// K2 (R21 v8, measured 42us): swapped QK^T flash attn, 64-row i-tiles,
// 4 blocks/CU, dbuf single-barrier, global bias, defer-max.
// ---------------------------------------------------------------------------
__global__ __launch_bounds__(256, 4) void attn_kernel(
    const unsigned short* __restrict__ Q, const unsigned short* __restrict__ K,
    const unsigned short* __restrict__ Vt, const float* __restrict__ pe,
    unsigned short* __restrict__ O) {
  __shared__ unsigned short Kt[2][64 * 64];  // [buf][j][k] swizzled, 16KB
  __shared__ unsigned short Vl[2][64 * 64];  // [buf][d][j] swizzled, 16KB
  __shared__ unsigned short Pl[4][1024];     // per wave [i=c][j], 8KB
  char* PlB = (char*)Pl;
  int t = threadIdx.x, lane = t & 63, wv = t >> 6;
  int c = lane & 15, r4 = lane >> 4;
  int swzid = (blockIdx.x & 7) * 128 + (blockIdx.x >> 3);
  int bm = swzid >> 4;
  int i0 = (swzid & 15) * 64;

  const unsigned short* Qb = Q + ((size_t)bm * HW + i0 + wv * 16) * Dd;
  bf16x8 qb[2];
#pragma unroll
  for (int kc = 0; kc < 2; ++kc)
    qb[kc] = *(const bf16x8*)(Qb + c * Dd + kc * 32 + r4 * 8);

  int ibase = i0 + wv * 16;
  int yi = ibase >> 5, xib = ibase & 31;
  int hb = 63 * (31 - yi) + 31 - xib - c + r4 * 4;

  f32x4 oacc[4];
  float m_run = -1e30f, l_run = 0.f;
#pragma unroll
  for (int nf = 0; nf < 4; ++nf) oacc[nf] = {0.f, 0.f, 0.f, 0.f};

  const unsigned short* Kg = K + (size_t)bm * HW * Dd;
  const unsigned short* Vg = Vt + (size_t)bm * Dd * HW;
  char* pb = PlB + wv * 2048 + c * 128;
  int swp = (c & 7) << 4;
  int srow = t >> 3, sc8 = t & 7;

  bf16x8 kreg[2], vreg[2];
  auto issue = [&](int j0) {
#pragma unroll
    for (int rep = 0; rep < 2; ++rep) {
      int row = srow + rep * 32;
      kreg[rep] = *(const bf16x8*)(Kg + (size_t)(j0 + row) * Dd + sc8 * 8);
      vreg[rep] = *(const bf16x8*)(Vg + (size_t)row * HW + j0 + sc8 * 8);
    }
  };
  auto stage = [&](int buf) {
#pragma unroll
    for (int rep = 0; rep < 2; ++rep) {
      int row = srow + rep * 32;
      *(bf16x8*)((char*)Kt[buf] + swz(row, sc8 * 16)) = kreg[rep];
      *(bf16x8*)((char*)Vl[buf] + swz(row, sc8 * 16)) = vreg[rep];
    }
  };

  issue(0);
  stage(0);
  issue(64);
  __syncthreads();

  int cur = 0;
  for (int jt = 0; jt < 16; ++jt) {
    int j0 = jt * 64;
    if (jt < 15) {
      stage(cur ^ 1);
      if (jt < 14) issue(j0 + 128);
    }
    char* KtB = (char*)Kt[cur];
    char* VtB = (char*)Vl[cur];

    f32x4 sacc[4];
    int tb = hb + 63 * (j0 >> 5);
#pragma unroll
    for (int jf = 0; jf < 4; ++jf) {
      int o = tb + (jf >> 1) * 63 + (jf & 1) * 16;
      sacc[jf] = {pe[o], pe[o + 1], pe[o + 2], pe[o + 3]};
    }
#pragma unroll
    for (int jf = 0; jf < 4; ++jf) {
      int row = jf * 16 + c, sw = (row & 7) << 4;
      bf16x8 kb0 = *(const bf16x8*)(KtB + row * 128 + ((r4 * 16) ^ sw));
      bf16x8 kb1 = *(const bf16x8*)(KtB + row * 128 + ((64 + r4 * 16) ^ sw));
      sacc[jf] = __builtin_amdgcn_mfma_f32_16x16x32_bf16(kb0, qb[0], sacc[jf], 0, 0, 0);
      sacc[jf] = __builtin_amdgcn_mfma_f32_16x16x32_bf16(kb1, qb[1], sacc[jf], 0, 0, 0);
    }
    float mx = fmaxf(
        fmaxf(fmaxf(fmaxf(sacc[0][0], sacc[0][1]), fmaxf(sacc[0][2], sacc[0][3])),
              fmaxf(fmaxf(sacc[1][0], sacc[1][1]), fmaxf(sacc[1][2], sacc[1][3]))),
        fmaxf(fmaxf(fmaxf(sacc[2][0], sacc[2][1]), fmaxf(sacc[2][2], sacc[2][3])),
              fmaxf(fmaxf(sacc[3][0], sacc[3][1]), fmaxf(sacc[3][2], sacc[3][3]))));
    mx = fmaxf(mx, __shfl_xor(mx, 16));
    mx = fmaxf(mx, __shfl_xor(mx, 32));
    if (!__all(mx <= m_run + 8.f)) {
      float mnew = fmaxf(m_run, mx);
      float sc = __builtin_amdgcn_exp2f((m_run - mnew) * LOG2E);
      m_run = mnew;
      l_run *= sc;
#pragma unroll
      for (int nf = 0; nf < 4; ++nf) oacc[nf] *= sc;
    }
    float ml = m_run * LOG2E;
    float ps = 0.f;
#pragma unroll
    for (int jf = 0; jf < 4; ++jf)
#pragma unroll
      for (int r = 0; r < 4; ++r) {
        float p = __builtin_amdgcn_exp2f(fmaf(sacc[jf][r], LOG2E, -ml));
        sacc[jf][r] = p;
        ps += p;
      }
    ps += __shfl_xor(ps, 16);
    ps += __shfl_xor(ps, 32);
    l_run += ps;
#pragma unroll
    for (int jf = 0; jf < 4; ++jf) {
      unsigned int w0 = pack2(sacc[jf][0], sacc[jf][1]);
      unsigned int w1 = pack2(sacc[jf][2], sacc[jf][3]);
      unsigned long long wd = (unsigned long long)w0 | ((unsigned long long)w1 << 32);
      *(unsigned long long*)(pb + ((jf * 32 + r4 * 8) ^ swp)) = wd;
    }
#pragma unroll
    for (int jk = 0; jk < 2; ++jk) {
      bf16x8 pa = *(const bf16x8*)(pb + ((jk * 64 + r4 * 16) ^ swp));
#pragma unroll
      for (int nf = 0; nf < 4; ++nf) {
        int row = nf * 16 + c, sw = (row & 7) << 4;
        bf16x8 vb = *(const bf16x8*)(VtB + row * 128 + ((jk * 64 + r4 * 16) ^ sw));
        oacc[nf] = __builtin_amdgcn_mfma_f32_16x16x32_bf16(vb, pa, oacc[nf], 0, 0, 0);
      }
    }
    if (jt < 15) {
      __syncthreads();
      cur ^= 1;
    }
  }

  __syncthreads();
  char* zone = ((wv < 2) ? (char*)Kt[0] : (char*)Vl[0]) + (wv & 1) * 4096;
  float inv = 1.f / l_run;
  int swc = (c & 7) << 4;
#pragma unroll
  for (int nf = 0; nf < 4; ++nf) {
    unsigned int d0 = pack2(oacc[nf][0] * inv, oacc[nf][1] * inv);
    unsigned int d1 = pack2(oacc[nf][2] * inv, oacc[nf][3] * inv);
    unsigned long long wd = (unsigned long long)d0 | ((unsigned long long)d1 << 32);
    *(unsigned long long*)(zone + c * 128 + ((nf * 32 + r4 * 8) ^ swc)) = wd;
  }
  __syncthreads();
  int rrow = lane >> 2, dq = lane & 3;
  int swr = (rrow & 7) << 4;
  size_t obase = ((size_t)bm * HW + i0 + wv * 16 + rrow) * Dd + dq * 16;
#pragma unroll
  for (int p = 0; p < 2; ++p) {
    bf16x8 vv = *(const bf16x8*)(zone + rrow * 128 + ((dq * 32 + p * 16) ^ swr));
    *(bf16x8*)(O + obase + p * 8) = vv;
  }
}

// ---------------------------------------------------------------------------
// K3 (v3 = v2 minus A-LDS): output projection. A-frags (O rows, 16B/lane)
// read DIRECT from global with 1-iter register prefetch; only B (W^T 64x64)
// dbuf-staged in LDS. LDS 16KB; single barrier per m-iter (B only).
// ---------------------------------------------------------------------------
__global__ __launch_bounds__(256, 2) void proj_kernel(
    const unsigned short* __restrict__ O, const float* __restrict__ W,
    const float* __restrict__ bias, float* __restrict__ out) {
  __shared__ unsigned short Bt[2][64 * 64];   // [buf][n][k] swizzled, 16KB
  int t = threadIdx.x, lane = t & 63, wv = t >> 6;
  int rb = blockIdx.x >> 3, n0 = (blockIdx.x & 7) * 64;
  int row0 = rb * 128;             // flat (b,pos); never crosses b
  int b = row0 >> 10, pos0 = row0 & 1023;
  int c = lane & 15, r4 = lane >> 4;
  int nt = t & 15, kt = t >> 4;    // B staging roles

  f32x4 acc[2][4];
#pragma unroll
  for (int g = 0; g < 2; ++g)
#pragma unroll
    for (int nf = 0; nf < 4; ++nf) acc[g][nf] = {0.f, 0.f, 0.f, 0.f};

  f32x4 wreg[4];
  bf16x8 aA[4], aB[4];  // A-frag dbuf: [g*2+kc] for rows wv*32+{c,16+c}

  auto issueW = [&](int m) {
#pragma unroll
    for (int r = 0; r < 4; ++r)
      wreg[r] = *(const f32x4*)(W + (size_t)(m * 64 + kt * 4 + r) * Cc + n0 + nt * 4);
  };
  auto issueA = [&](bf16x8 (&ar)[4], int m) {
    const unsigned short* Ob = O + ((size_t)(b * 8 + m) * HW + pos0) * Dd;
#pragma unroll
    for (int g = 0; g < 2; ++g)
#pragma unroll
      for (int kc = 0; kc < 2; ++kc)
        ar[g * 2 + kc] = *(const bf16x8*)(Ob + (size_t)(wv * 32 + g * 16 + c) * Dd +
                                          kc * 32 + r4 * 8);
  };
  auto stageB = [&](int buf) {
    char* BtB = (char*)Bt[buf];
#pragma unroll
    for (int e = 0; e < 4; ++e) {
      bf16x4 bt = {(short)f2bf(wreg[0][e]), (short)f2bf(wreg[1][e]),
                   (short)f2bf(wreg[2][e]), (short)f2bf(wreg[3][e])};
      *(bf16x4*)(BtB + swz(nt * 4 + e, kt * 8)) = bt;
    }
  };

  issueW(0);
  issueA(aA, 0);
  stageB(0);
  issueW(1);
  issueA(aB, 1);
  __syncthreads();

  int cur = 0;
  for (int m = 0; m < 8; ++m) {
    if (m < 7) {
      stageB(cur ^ 1);
      if (m < 6) issueW(m + 2);
    }
    char* BtB = (char*)Bt[cur];
    bf16x8* ar = (m & 1) ? aB : aA;
#pragma unroll
    for (int kc = 0; kc < 2; ++kc) {
#pragma unroll
      for (int nf = 0; nf < 4; ++nf) {
        bf16x8 bb = *(const bf16x8*)(BtB + swz(nf * 16 + c, kc * 64 + r4 * 16));
        acc[0][nf] = __builtin_amdgcn_mfma_f32_16x16x32_bf16(ar[kc], bb, acc[0][nf], 0, 0, 0);
        acc[1][nf] = __builtin_amdgcn_mfma_f32_16x16x32_bf16(ar[2 + kc], bb, acc[1][nf], 0, 0, 0);
      }
    }
    if (m < 6) issueA((m & 1) ? aB : aA, m + 2);  // prefetch A for m+2
    if (m < 7) {
      __syncthreads();
      cur ^= 1;
    }
  }

  float bv[4];
#pragma unroll
  for (int nf = 0; nf < 4; ++nf) bv[nf] = bias[n0 + nf * 16 + c];
#pragma unroll
  for (int g = 0; g < 2; ++g) {
#pragma unroll
    for (int reg = 0; reg < 4; ++reg) {
      int row = row0 + wv * 32 + g * 16 + r4 * 4 + reg;
#pragma unroll
      for (int nf = 0; nf < 4; ++nf)
        out[(size_t)row * Cc + n0 + nf * 16 + c] = acc[g][nf][reg] + bv[nf];
    }
  }
}

extern "C" void kernel_launch(void* const* d_in, const int* in_sizes, int n_in,
                              void* d_out, int out_size, void* d_ws, size_t ws_size,
                              hipStream_t stream) {
  const float* x      = (const float*)d_in[0];
  const float* qkv_w  = (const float*)d_in[1];
  const float* qkv_b  = (const float*)d_in[2];
  const float* pos_emb= (const float*)d_in[3];
  const float* ht_w   = (const float*)d_in[4];
  const float* ht_b   = (const float*)d_in[5];
  float* out = (float*)d_out;

  const size_t NQ = (size_t)BM * HW * Dd;  // 4,194,304 elements
  unsigned short* Qw  = (unsigned short*)d_ws;
  unsigned short* Kw  = Qw + NQ;
  unsigned short* Vtw = Kw + NQ;           // V^T [bm][d][pos], 8 MB
  unsigned short* Ow  = Vtw + NQ;          // bf16 O [bm][pos][d], 8 MB

  hipLaunchKernelGGL(qkv_kernel, dim3(256), dim3(256), 0, stream,
                     x, qkv_w, qkv_b, Qw, Kw, Vtw);
  hipLaunchKernelGGL(attn_kernel, dim3(1024), dim3(256), 0, stream,
                     Qw, Kw, Vtw, pos_emb, Ow);
  hipLaunchKernelGGL(proj_kernel, dim3(512), dim3(256), 0, stream,
                     Ow, ht_w, ht_b, out);
}